// Round 1
// baseline (2988.594 us; speedup 1.0000x reference)
//
#include <hip/hip_runtime.h>
#include <hip/hip_bf16.h>

#define Vv 32000
#define Ee 256
#define Hh 256
#define Bb 32
#define TEe 128
#define TDd 64

typedef __attribute__((ext_vector_type(4))) float f32x4;
typedef __attribute__((ext_vector_type(8))) short short8;
typedef __attribute__((ext_vector_type(2))) unsigned int uint2v;
typedef __attribute__((ext_vector_type(4))) unsigned int uint4v;

static __device__ __forceinline__ unsigned short f2bf(float f){
  unsigned u = __float_as_uint(f);
  u += 0x7fffu + ((u >> 16) & 1u);           // round-to-nearest-even
  return (unsigned short)(u >> 16);
}
static __device__ __forceinline__ unsigned pack2(float a, float b){
  return ((unsigned)f2bf(b) << 16) | (unsigned)f2bf(a);
}
// dot of 8 packed bf16 (uint4) with 8 f32
static __device__ __forceinline__ float dot8(uint4v u, const float* hh){
  float s = 0.f;
  #pragma unroll
  for (int i = 0; i < 4; ++i){
    unsigned w = u[i];
    s = fmaf(__uint_as_float(w << 16),        hh[2*i],   s);
    s = fmaf(__uint_as_float(w & 0xffff0000u), hh[2*i+1], s);
  }
  return s;
}
static __device__ __forceinline__ float sigmoidf_(float x){
  return 1.f / (1.f + __expf(-x));
}

// ---------------- small prep kernels ----------------
__global__ void k_sizes(const int* __restrict__ enc_in, int* __restrict__ sizes){
  int b = threadIdx.x;
  if (b < Bb){
    int c = 0;
    for (int t = 0; t < TEe; ++t) c += (enc_in[b*TEe + t] > 0);
    sizes[b] = c;
  }
}

__global__ void k_gather(const int* __restrict__ tok, const float* __restrict__ embW,
                         float* __restrict__ out, int rows){
  int i = blockIdx.x * 256 + threadIdx.x;
  int r = i >> 8, c = i & 255;
  if (r < rows) out[i] = embW[(size_t)tok[r]*Ee + c];
}

// strided f32 -> bf16 (cols = 1<<cshift)
__global__ void k_extract_bf16(const float* __restrict__ src, unsigned short* __restrict__ dst,
                               int n, int ld, int off, int cshift){
  int i = blockIdx.x * 256 + threadIdx.x;
  if (i < n){
    int r = i >> cshift, c = i & ((1 << cshift) - 1);
    dst[i] = f2bf(src[(size_t)r*ld + off + c]);
  }
}

// ---------------- bf16 MFMA GEMM: C[M,N] = A[M,K] * B^T + bias ----------------
template<bool A_BF16, bool B_BF16, bool B_KMAJOR, bool OUT_BF16>
__global__ __launch_bounds__(256) void k_gemm(
  const void* __restrict__ Av, const void* __restrict__ Bv,
  const float* __restrict__ bias, void* __restrict__ Cv,
  int M, int N, int K, int lda, int ldb, int ldc)
{
  __shared__ unsigned short lA[128*40];   // row stride 40 bf16 (pad vs bank conflicts)
  __shared__ unsigned short lB[128*40];
  const int tid  = threadIdx.x;
  const int lane = tid & 63;
  const int w = tid >> 6, wr = w >> 1, wc = w & 1;
  const int m0 = blockIdx.y * 128, n0 = blockIdx.x * 128;
  f32x4 acc[4][4];
  #pragma unroll
  for (int i = 0; i < 4; ++i)
    #pragma unroll
    for (int j = 0; j < 4; ++j) acc[i][j] = (f32x4){0.f,0.f,0.f,0.f};

  for (int k0 = 0; k0 < K; k0 += 32){
    if (A_BF16){
      const unsigned short* A = (const unsigned short*)Av;
      #pragma unroll
      for (int it = 0; it < 2; ++it){
        int idx = tid + it*256; int r = idx >> 2, q = idx & 3;
        *(uint4v*)&lA[r*40 + q*8] = *(const uint4v*)(A + (size_t)(m0+r)*lda + k0 + q*8);
      }
    } else {
      const float* A = (const float*)Av;
      #pragma unroll
      for (int it = 0; it < 4; ++it){
        int idx = tid + it*256; int r = idx >> 3, q = idx & 7;
        f32x4 v = *(const f32x4*)(A + (size_t)(m0+r)*lda + k0 + q*4);
        uint2v pk; pk[0] = pack2(v[0], v[1]); pk[1] = pack2(v[2], v[3]);
        *(uint2v*)&lA[r*40 + q*4] = pk;
      }
    }
    if (B_KMAJOR){      // B given as [K,N] f32 (e.g. W2_w)
      const float* Bp = (const float*)Bv;
      #pragma unroll
      for (int it = 0; it < 4; ++it){
        int idx = tid + it*256; int kk = idx >> 5, nq = idx & 31;
        f32x4 v = *(const f32x4*)(Bp + (size_t)(k0+kk)*ldb + n0 + nq*4);
        #pragma unroll
        for (int s2 = 0; s2 < 4; ++s2) lB[(nq*4+s2)*40 + kk] = f2bf(v[s2]);
      }
    } else if (B_BF16){
      const unsigned short* Bp = (const unsigned short*)Bv;
      #pragma unroll
      for (int it = 0; it < 2; ++it){
        int idx = tid + it*256; int r = idx >> 2, q = idx & 3;
        *(uint4v*)&lB[r*40 + q*8] = *(const uint4v*)(Bp + (size_t)(n0+r)*ldb + k0 + q*8);
      }
    } else {
      const float* Bp = (const float*)Bv;
      #pragma unroll
      for (int it = 0; it < 4; ++it){
        int idx = tid + it*256; int r = idx >> 3, q = idx & 7;
        f32x4 v = *(const f32x4*)(Bp + (size_t)(n0+r)*ldb + k0 + q*4);
        uint2v pk; pk[0] = pack2(v[0], v[1]); pk[1] = pack2(v[2], v[3]);
        *(uint2v*)&lB[r*40 + q*4] = pk;
      }
    }
    __syncthreads();
    short8 av[4], bv[4];
    #pragma unroll
    for (int i = 0; i < 4; ++i)
      av[i] = *(const short8*)&lA[(wr*64 + i*16 + (lane&15))*40 + (lane>>4)*8];
    #pragma unroll
    for (int j = 0; j < 4; ++j)
      bv[j] = *(const short8*)&lB[(wc*64 + j*16 + (lane&15))*40 + (lane>>4)*8];
    #pragma unroll
    for (int i = 0; i < 4; ++i)
      #pragma unroll
      for (int j = 0; j < 4; ++j)
        acc[i][j] = __builtin_amdgcn_mfma_f32_16x16x32_bf16(av[i], bv[j], acc[i][j], 0, 0, 0);
    __syncthreads();
  }
  #pragma unroll
  for (int i = 0; i < 4; ++i){
    #pragma unroll
    for (int j = 0; j < 4; ++j){
      int col = n0 + wc*64 + j*16 + (lane & 15);
      float bb = bias ? bias[col] : 0.f;
      #pragma unroll
      for (int r = 0; r < 4; ++r){
        int row = m0 + wr*64 + i*16 + (lane>>4)*4 + r;
        float v = acc[i][j][r] + bb;
        if (OUT_BF16) ((unsigned short*)Cv)[(size_t)row*ldc + col] = f2bf(v);
        else          ((float*)Cv)[(size_t)row*ldc + col] = v;
      }
    }
  }
}

// ---------------- encoder recurrence: 64 blocks = (dir, batch) ----------------
__global__ __launch_bounds__(256) void k_encoder(
  const unsigned short* __restrict__ Whf, const unsigned short* __restrict__ Whb,
  const float* __restrict__ bhf, const float* __restrict__ bhb,
  const float* __restrict__ gif, const float* __restrict__ gib,
  float* __restrict__ encoded)
{
  const int dir = blockIdx.x & 1, b = blockIdx.x >> 1;
  const unsigned short* Wh = dir ? Whb : Whf;
  const float* bh = dir ? bhb : bhf;
  const float* gi = dir ? gib : gif;
  const int j = threadIdx.x;
  __shared__ float h[Hh];
  const float bh0 = bh[j], bh1 = bh[j+256], bh2 = bh[j+512];
  const unsigned short* w0 = Wh + (size_t)j*256;
  const unsigned short* w1 = Wh + (size_t)(j+256)*256;
  const unsigned short* w2 = Wh + (size_t)(j+512)*256;
  h[j] = 0.f;
  __syncthreads();
  for (int s = 0; s < TEe; ++s){
    const int t = dir ? (TEe-1-s) : s;
    float a0 = 0.f, a1 = 0.f, a2 = 0.f;
    #pragma unroll 8
    for (int k = 0; k < 256; k += 8){
      float hr[8];
      *(f32x4*)&hr[0] = *(const f32x4*)&h[k];
      *(f32x4*)&hr[4] = *(const f32x4*)&h[k+4];
      a0 += dot8(*(const uint4v*)(w0 + k), hr);
      a1 += dot8(*(const uint4v*)(w1 + k), hr);
      a2 += dot8(*(const uint4v*)(w2 + k), hr);
    }
    const float* grow = gi + (size_t)(b*TEe + t)*768;
    const float r = sigmoidf_(grow[j]     + a0 + bh0);
    const float z = sigmoidf_(grow[j+256] + a1 + bh1);
    const float n = tanhf(grow[j+512] + r*(a2 + bh2));
    const float hprev = h[j];
    const float hnew = (1.f - z)*n + z*hprev;
    __syncthreads();
    h[j] = hnew;
    encoded[(size_t)(b*TEe + t)*512 + dir*256 + j] = hnew;
    __syncthreads();
  }
}

// encb2[r] = encoded[r,:512] . W2_b
__global__ void k_encb2(const float* __restrict__ encoded, const float* __restrict__ W2b,
                        float* __restrict__ encb2){
  int r = blockIdx.x, l = threadIdx.x;  // 64 threads
  const float* e = encoded + (size_t)r*512;
  float s = 0.f;
  for (int k = l; k < 512; k += 64) s += e[k]*W2b[k];
  for (int off = 32; off; off >>= 1) s += __shfl_down(s, off);
  if (l == 0) encb2[r] = s;
}

// ENC_PROJ f32 [B*TE,768] -> PROJT bf16 [B][768][TE]
__global__ void k_transpose_proj(const float* __restrict__ in, unsigned short* __restrict__ out){
  int i = blockIdx.x * 256 + threadIdx.x;
  if (i < Bb*768*TEe){
    int t = i & (TEe-1);
    int n = (i >> 7) % 768;
    int b = i / (768*TEe);
    out[i] = f2bf(in[(size_t)(b*TEe + t)*768 + n]);
  }
}

__global__ void k_hinit(const float* __restrict__ encoded, const int* __restrict__ sizes,
                        const float* __restrict__ W1w, const float* __restrict__ W1b,
                        float* __restrict__ h0){
  int b = blockIdx.x, o = threadIdx.x;  // 256 threads
  int idx = sizes[b] - 1;
  idx = idx < 0 ? 0 : (idx > TEe-1 ? TEe-1 : idx);
  const float* ls = encoded + (size_t)(b*TEe + idx)*512;
  const float* wv = W1w + (size_t)o*512;
  float s = W1b[o];
  for (int k = 0; k < 512; k += 4){
    f32x4 a = *(const f32x4*)(ls + k);
    f32x4 w4 = *(const f32x4*)(wv + k);
    s = fmaf(a[0],w4[0], fmaf(a[1],w4[1], fmaf(a[2],w4[2], fmaf(a[3],w4[3], s))));
  }
  h0[b*256 + o] = s;
}

// ---------------- decoder: 32 blocks = batch ----------------
__global__ __launch_bounds__(256) void k_decoder(
  const unsigned short* __restrict__ Whd, const float* __restrict__ bhd,
  const float* __restrict__ gidx,            // [B][TD][768] f32 (includes bi_d)
  const unsigned short* __restrict__ encw2,  // [B*TE][256] bf16
  const float* __restrict__ encb2,           // [B*TE]
  const unsigned short* __restrict__ projt,  // [B][768][TE] bf16
  const float* __restrict__ h0,
  unsigned short* __restrict__ outs_bf)      // [B][TD][256] bf16
{
  const int b = blockIdx.x, j = threadIdx.x;
  __shared__ float h[Hh];
  __shared__ float p[TEe];
  const float bh0 = bhd[j], bh1 = bhd[j+256], bh2 = bhd[j+512];
  const unsigned short* w0 = Whd + (size_t)j*256;
  const unsigned short* w1 = Whd + (size_t)(j+256)*256;
  const unsigned short* w2 = Whd + (size_t)(j+512)*256;
  const unsigned short* pt0 = projt + ((size_t)b*768 + j)*TEe;
  const unsigned short* pt1 = projt + ((size_t)b*768 + j + 256)*TEe;
  const unsigned short* pt2 = projt + ((size_t)b*768 + j + 512)*TEe;
  float gc0 = 0.f, gc1 = 0.f, gc2 = 0.f;     // Wi_ctx @ ctx (ctx_init = 0)
  h[j] = h0[b*256 + j];
  __syncthreads();
  for (int t = 0; t < TDd; ++t){
    // GRU cell: gh = Wh_d h + bh
    float a0 = 0.f, a1 = 0.f, a2 = 0.f;
    #pragma unroll 8
    for (int k = 0; k < 256; k += 8){
      float hr[8];
      *(f32x4*)&hr[0] = *(const f32x4*)&h[k];
      *(f32x4*)&hr[4] = *(const f32x4*)&h[k+4];
      a0 += dot8(*(const uint4v*)(w0 + k), hr);
      a1 += dot8(*(const uint4v*)(w1 + k), hr);
      a2 += dot8(*(const uint4v*)(w2 + k), hr);
    }
    const float* grow = gidx + (size_t)(b*TDd + t)*768;
    const float r = sigmoidf_(grow[j]     + gc0 + a0 + bh0);
    const float z = sigmoidf_(grow[j+256] + gc1 + a1 + bh1);
    const float n = tanhf(grow[j+512] + gc2 + r*(a2 + bh2));
    const float hprev = h[j];
    const float hnew = (1.f - z)*n + z*hprev;
    __syncthreads();
    h[j] = hnew;
    outs_bf[(size_t)(b*TDd + t)*256 + j] = f2bf(hnew);
    __syncthreads();
    // scores_pre[tt] = ENC_W2[b,tt,:] . h_new + encb2[b,tt]
    if (j < TEe){
      const unsigned short* erow = encw2 + (size_t)(b*TEe + j)*256;
      float s = encb2[b*TEe + j];
      #pragma unroll 8
      for (int k = 0; k < 256; k += 8){
        float hr[8];
        *(f32x4*)&hr[0] = *(const f32x4*)&h[k];
        *(f32x4*)&hr[4] = *(const f32x4*)&h[k+4];
        s += dot8(*(const uint4v*)(erow + k), hr);
      }
      p[j] = s;
    }
    __syncthreads();
    // softmax over 128 (wave 0)
    if (j < 64){
      float m = fmaxf(p[j], p[j+64]);
      for (int off = 32; off; off >>= 1) m = fmaxf(m, __shfl_xor(m, off));
      float e0 = __expf(p[j] - m), e1 = __expf(p[j+64] - m);
      float ssum = e0 + e1;
      for (int off = 32; off; off >>= 1) ssum += __shfl_xor(ssum, off);
      float inv = 1.f / ssum;
      p[j] = e0*inv; p[j+64] = e1*inv;
    }
    __syncthreads();
    // gi_ctx for NEXT step: gc = p @ ENC_PROJ[b]  (== ctx @ Wi_ctx^T)
    gc0 = gc1 = gc2 = 0.f;
    #pragma unroll 4
    for (int tt = 0; tt < TEe; tt += 8){
      float pr[8];
      *(f32x4*)&pr[0] = *(const f32x4*)&p[tt];
      *(f32x4*)&pr[4] = *(const f32x4*)&p[tt+4];
      gc0 += dot8(*(const uint4v*)(pt0 + tt), pr);
      gc1 += dot8(*(const uint4v*)(pt1 + tt), pr);
      gc2 += dot8(*(const uint4v*)(pt2 + tt), pr);
    }
    __syncthreads();   // protect p before next iteration rewrites it
  }
}

extern "C" void kernel_launch(void* const* d_in, const int* in_sizes, int n_in,
                              void* d_out, int out_size, void* d_ws, size_t ws_size,
                              hipStream_t stream)
{
  (void)in_sizes; (void)n_in; (void)out_size;
  const int*   enc_in = (const int*)d_in[0];
  const int*   dec_in = (const int*)d_in[1];
  const float* embW   = (const float*)d_in[2];
  const float* Wi_f   = (const float*)d_in[3];
  const float* Wh_f   = (const float*)d_in[4];
  const float* bi_f   = (const float*)d_in[5];
  const float* bh_f   = (const float*)d_in[6];
  const float* Wi_b   = (const float*)d_in[7];
  const float* Wh_b   = (const float*)d_in[8];
  const float* bi_b   = (const float*)d_in[9];
  const float* bh_b   = (const float*)d_in[10];
  const float* Wi_d   = (const float*)d_in[11];
  const float* Wh_d   = (const float*)d_in[12];
  const float* bi_d   = (const float*)d_in[13];
  const float* bh_d   = (const float*)d_in[14];
  const float* W1_w   = (const float*)d_in[15];
  const float* W1_b   = (const float*)d_in[16];
  const float* W2_w   = (const float*)d_in[17];
  const float* W2_b   = (const float*)d_in[18];
  const float* lin_w  = (const float*)d_in[19];
  const float* lin_b  = (const float*)d_in[20];

  // d_out (262 MB) doubles as scratch; every region below is fully rewritten
  // each call and dead before the final GEMM overwrites all of d_out.
  char* scr = (char*)d_out;
  float* emb_enc = (float*)(scr + 0);          //  4,194,304 B
  float* emb_dec = (float*)(scr + 4194304);    //  2,097,152
  float* gi_f    = (float*)(scr + 6291456);    // 12,582,912
  float* gi_b    = (float*)(scr + 18874368);   // 12,582,912
  float* gi_dx   = (float*)(scr + 31457280);   //  6,291,456
  float* enc     = (float*)(scr + 37748736);   //  8,388,608
  float* projf   = (float*)(scr + 46137344);   // 12,582,912
  unsigned short* whf_bf = (unsigned short*)(scr + 58720256);
  unsigned short* whb_bf = (unsigned short*)(scr + 59113472);
  unsigned short* whd_bf = (unsigned short*)(scr + 59506688);
  unsigned short* encw2  = (unsigned short*)(scr + 59899904);
  unsigned short* projt  = (unsigned short*)(scr + 61997056);
  float* encb2 = (float*)(scr + 68288512);
  int*   sizes = (int*)(scr + 68304896);
  float* h0    = (float*)(scr + 68305024);

  unsigned short* outs_bf = (unsigned short*)d_ws;                 // 1 MB
  unsigned short* lin_bf  = (unsigned short*)((char*)d_ws + (1<<20));
  const bool big = ws_size >= (size_t)(1<<20) + 16384000u + 1024u;

  k_sizes<<<1, 32, 0, stream>>>(enc_in, sizes);
  k_gather<<<Bb*TEe, 256, 0, stream>>>(enc_in, embW, emb_enc, Bb*TEe);
  k_gather<<<Bb*TDd, 256, 0, stream>>>(dec_in, embW, emb_dec, Bb*TDd);
  k_extract_bf16<<<768, 256, 0, stream>>>(Wh_f, whf_bf, 768*256, 256, 0, 8);
  k_extract_bf16<<<768, 256, 0, stream>>>(Wh_b, whb_bf, 768*256, 256, 0, 8);
  k_extract_bf16<<<768, 256, 0, stream>>>(Wh_d, whd_bf, 768*256, 256, 0, 8);
  if (big) k_extract_bf16<<<32000, 256, 0, stream>>>(lin_w, lin_bf, 32000*256, 256, 0, 8);

  // gi_f / gi_b / gi_dx  (input projections incl. bias)
  k_gemm<false,false,false,false><<<dim3(6,32), 256, 0, stream>>>(
      emb_enc, Wi_f, bi_f, gi_f, 4096, 768, 256, 256, 256, 768);
  k_gemm<false,false,false,false><<<dim3(6,32), 256, 0, stream>>>(
      emb_enc, Wi_b, bi_b, gi_b, 4096, 768, 256, 256, 256, 768);
  k_gemm<false,false,false,false><<<dim3(6,16), 256, 0, stream>>>(
      emb_dec, Wi_d + 512, bi_d, gi_dx, 2048, 768, 256, 256, 768, 768);

  k_encoder<<<64, 256, 0, stream>>>(whf_bf, whb_bf, bh_f, bh_b, gi_f, gi_b, enc);
  k_encb2<<<Bb*TEe, 64, 0, stream>>>(enc, W2_b, encb2);

  // ENC_W2 = encoded @ W2  (B is K-major) -> bf16
  k_gemm<false,false,true,true><<<dim3(2,32), 256, 0, stream>>>(
      enc, W2_w, nullptr, encw2, 4096, 256, 512, 512, 256, 256);
  // ENC_PROJ = encoded @ Wi_ctx^T  (Wi_d cols 0:512, row stride 768)
  k_gemm<false,false,false,false><<<dim3(6,32), 256, 0, stream>>>(
      enc, Wi_d, nullptr, projf, 4096, 768, 512, 512, 768, 768);
  k_transpose_proj<<<(Bb*768*TEe)/256, 256, 0, stream>>>(projf, projt);
  k_hinit<<<Bb, 256, 0, stream>>>(enc, sizes, W1_w, W1_b, h0);

  k_decoder<<<Bb, 256, 0, stream>>>(whd_bf, bh_d, gi_dx, encw2, encb2, projt, h0, outs_bf);

  // logits = outs @ lin_w^T + lin_b  -> d_out [2048, 32000] f32
  if (big)
    k_gemm<true,true,false,false><<<dim3(250,16), 256, 0, stream>>>(
        outs_bf, lin_bf, lin_b, d_out, 2048, 32000, 256, 256, 256, 32000);
  else
    k_gemm<true,false,false,false><<<dim3(250,16), 256, 0, stream>>>(
        outs_bf, lin_w, lin_b, d_out, 2048, 32000, 256, 256, 256, 32000);
}

// Round 3
// 2159.730 us; speedup vs baseline: 1.3838x; 1.3838x over previous
//
#include <hip/hip_runtime.h>
#include <hip/hip_bf16.h>

#define Vv 32000
#define Ee 256
#define Hh 256
#define Bb 32
#define TEe 128
#define TDd 64

typedef __attribute__((ext_vector_type(4))) float f32x4;
typedef __attribute__((ext_vector_type(8))) short short8;
typedef __attribute__((ext_vector_type(2))) unsigned int uint2v;
typedef __attribute__((ext_vector_type(4))) unsigned int uint4v;

static __device__ __forceinline__ unsigned short f2bf(float f){
  unsigned u = __float_as_uint(f);
  u += 0x7fffu + ((u >> 16) & 1u);           // round-to-nearest-even
  return (unsigned short)(u >> 16);
}
static __device__ __forceinline__ unsigned pack2(float a, float b){
  return ((unsigned)f2bf(b) << 16) | (unsigned)f2bf(a);
}
// dot of 8 packed bf16 (uint4) with 8 f32
static __device__ __forceinline__ float dot8(uint4v u, const float* hh){
  float s = 0.f;
  #pragma unroll
  for (int i = 0; i < 4; ++i){
    unsigned w = u[i];
    s = fmaf(__uint_as_float(w << 16),        hh[2*i],   s);
    s = fmaf(__uint_as_float(w & 0xffff0000u), hh[2*i+1], s);
  }
  return s;
}
static __device__ __forceinline__ float sigmoidf_(float x){
  return 1.f / (1.f + __expf(-x));
}

// ---------------- small prep kernels ----------------
__global__ void k_sizes(const int* __restrict__ enc_in, int* __restrict__ sizes){
  int b = threadIdx.x;
  if (b < Bb){
    int c = 0;
    for (int t = 0; t < TEe; ++t) c += (enc_in[b*TEe + t] > 0);
    sizes[b] = c;
  }
}

__global__ void k_gather(const int* __restrict__ tok, const float* __restrict__ embW,
                         float* __restrict__ out, int rows){
  int i = blockIdx.x * 256 + threadIdx.x;
  int r = i >> 8, c = i & 255;
  if (r < rows) out[i] = embW[(size_t)tok[r]*Ee + c];
}

// f32 [rows][256] -> bf16 row-major
__global__ void k_extract_bf16(const float* __restrict__ src, unsigned short* __restrict__ dst,
                               int n){
  int i = blockIdx.x * 256 + threadIdx.x;
  if (i < n) dst[i] = f2bf(src[i]);
}

// f32 [rows][256] -> chunked bf16 [32][rows][8]  (kb-major for coalesced streaming)
__global__ void k_chunkw(const float* __restrict__ src, unsigned short* __restrict__ dst, int rows){
  int idx = blockIdx.x * 256 + threadIdx.x;
  if (idx < rows * 256){
    int i = idx & 7, r = (idx >> 3) % rows, kb = idx / (rows * 8);
    dst[idx] = f2bf(src[(size_t)r*256 + kb*8 + i]);
  }
}

// projf f32 [B*TE][768] -> chunked bf16 [B][16][768][8]
__global__ void k_projchunk(const float* __restrict__ in, unsigned short* __restrict__ out){
  int idx = blockIdx.x * 256 + threadIdx.x;     // total B*16*768*8
  int i = idx & 7;
  int t1 = idx >> 3;
  int n = t1 % 768;
  int t2 = t1 / 768;
  int kb = t2 & 15, b = t2 >> 4;
  out[idx] = f2bf(in[(size_t)(b*TEe + kb*8 + i)*768 + n]);
}

// ---------------- bf16 MFMA GEMM: C[M,N] = A[M,K] * B^T + bias ----------------
template<bool A_BF16, bool B_BF16, bool B_KMAJOR, bool OUT_BF16>
__global__ __launch_bounds__(256) void k_gemm(
  const void* __restrict__ Av, const void* __restrict__ Bv,
  const float* __restrict__ bias, void* __restrict__ Cv,
  int M, int N, int K, int lda, int ldb, int ldc)
{
  __shared__ unsigned short lA[128*40];
  __shared__ unsigned short lB[128*40];
  const int tid  = threadIdx.x;
  const int lane = tid & 63;
  const int w = tid >> 6, wr = w >> 1, wc = w & 1;
  const int m0 = blockIdx.y * 128, n0 = blockIdx.x * 128;
  f32x4 acc[4][4];
  #pragma unroll
  for (int i = 0; i < 4; ++i)
    #pragma unroll
    for (int j = 0; j < 4; ++j) acc[i][j] = (f32x4){0.f,0.f,0.f,0.f};

  for (int k0 = 0; k0 < K; k0 += 32){
    if (A_BF16){
      const unsigned short* A = (const unsigned short*)Av;
      #pragma unroll
      for (int it = 0; it < 2; ++it){
        int idx = tid + it*256; int r = idx >> 2, q = idx & 3;
        *(uint4v*)&lA[r*40 + q*8] = *(const uint4v*)(A + (size_t)(m0+r)*lda + k0 + q*8);
      }
    } else {
      const float* A = (const float*)Av;
      #pragma unroll
      for (int it = 0; it < 4; ++it){
        int idx = tid + it*256; int r = idx >> 3, q = idx & 7;
        f32x4 v = *(const f32x4*)(A + (size_t)(m0+r)*lda + k0 + q*4);
        uint2v pk; pk[0] = pack2(v[0], v[1]); pk[1] = pack2(v[2], v[3]);
        *(uint2v*)&lA[r*40 + q*4] = pk;
      }
    }
    if (B_KMAJOR){
      const float* Bp = (const float*)Bv;
      #pragma unroll
      for (int it = 0; it < 4; ++it){
        int idx = tid + it*256; int kk = idx >> 5, nq = idx & 31;
        f32x4 v = *(const f32x4*)(Bp + (size_t)(k0+kk)*ldb + n0 + nq*4);
        #pragma unroll
        for (int s2 = 0; s2 < 4; ++s2) lB[(nq*4+s2)*40 + kk] = f2bf(v[s2]);
      }
    } else if (B_BF16){
      const unsigned short* Bp = (const unsigned short*)Bv;
      #pragma unroll
      for (int it = 0; it < 2; ++it){
        int idx = tid + it*256; int r = idx >> 2, q = idx & 3;
        *(uint4v*)&lB[r*40 + q*8] = *(const uint4v*)(Bp + (size_t)(n0+r)*ldb + k0 + q*8);
      }
    } else {
      const float* Bp = (const float*)Bv;
      #pragma unroll
      for (int it = 0; it < 4; ++it){
        int idx = tid + it*256; int r = idx >> 3, q = idx & 7;
        f32x4 v = *(const f32x4*)(Bp + (size_t)(n0+r)*ldb + k0 + q*4);
        uint2v pk; pk[0] = pack2(v[0], v[1]); pk[1] = pack2(v[2], v[3]);
        *(uint2v*)&lB[r*40 + q*4] = pk;
      }
    }
    __syncthreads();
    short8 av[4], bv[4];
    #pragma unroll
    for (int i = 0; i < 4; ++i)
      av[i] = *(const short8*)&lA[(wr*64 + i*16 + (lane&15))*40 + (lane>>4)*8];
    #pragma unroll
    for (int j = 0; j < 4; ++j)
      bv[j] = *(const short8*)&lB[(wc*64 + j*16 + (lane&15))*40 + (lane>>4)*8];
    #pragma unroll
    for (int i = 0; i < 4; ++i)
      #pragma unroll
      for (int j = 0; j < 4; ++j)
        acc[i][j] = __builtin_amdgcn_mfma_f32_16x16x32_bf16(av[i], bv[j], acc[i][j], 0, 0, 0);
    __syncthreads();
  }
  #pragma unroll
  for (int i = 0; i < 4; ++i){
    #pragma unroll
    for (int j = 0; j < 4; ++j){
      int col = n0 + wc*64 + j*16 + (lane & 15);
      float bb = bias ? bias[col] : 0.f;
      #pragma unroll
      for (int r = 0; r < 4; ++r){
        int row = m0 + wr*64 + i*16 + (lane>>4)*4 + r;
        float v = acc[i][j][r] + bb;
        if (OUT_BF16) ((unsigned short*)Cv)[(size_t)row*ldc + col] = f2bf(v);
        else          ((float*)Cv)[(size_t)row*ldc + col] = v;
      }
    }
  }
}

// ---------------- encoder recurrence: 64 blocks = (dir, batch), 768 threads ----------------
// Weights arrive CHUNKED: [32][768][8] bf16. Rows [0,EJL) LDS-resident (XOR-swizzled).
#define EJL 248
__global__ __launch_bounds__(768) void k_encoder(
  const unsigned short* __restrict__ Whf, const unsigned short* __restrict__ Whb,
  const float* __restrict__ bhf, const float* __restrict__ bhb,
  const float* __restrict__ gif, const float* __restrict__ gib,
  float* __restrict__ encoded)
{
  extern __shared__ char smem[];
  unsigned short* lw = (unsigned short*)smem;                 // EJL*256*2 = 126976
  float* h   = (float*)(smem + EJL*512);                      // 1024
  float* ash = (float*)(smem + EJL*512 + 1024);               // 3072
  const int dir = blockIdx.x & 1, b = blockIdx.x >> 1;
  const unsigned short* Wh = dir ? Whb : Whf;
  const float* bh = dir ? bhb : bhf;
  const float* gi = dir ? gib : gif;
  const int j = threadIdx.x;
  // stage LDS rows: lw[r][q^] = chunk(q, r)
  for (int cc = j; cc < EJL*32; cc += 768){
    int r = cc >> 5, q = cc & 31;
    *(uint4v*)&lw[(r*32 + (q ^ (r & 31)))*8] = *(const uint4v*)(Wh + (size_t)q*6144 + r*8);
  }
  if (j < 256) h[j] = 0.f;
  const float bhj = bh[j];
  const int jx = j & 31;
  __syncthreads();
  for (int s = 0; s < TEe; ++s){
    const int t = dir ? (TEe-1-s) : s;
    float g0 = 0.f, g1 = 0.f, g2 = 0.f;
    if (j < 256){
      const float* grow = gi + (size_t)(b*TEe + t)*768;
      g0 = grow[j]; g1 = grow[j+256]; g2 = grow[j+512];
    }
    float a = bhj;
    if (j < EJL){
      const unsigned short* lwr = lw + j*256;
      #pragma unroll
      for (int q = 0; q < 32; ++q){
        float hr[8];
        *(f32x4*)&hr[0] = *(const f32x4*)&h[q*8];
        *(f32x4*)&hr[4] = *(const f32x4*)&h[q*8+4];
        a += dot8(*(const uint4v*)(lwr + ((q ^ jx) << 3)), hr);
      }
    } else {
      #pragma unroll
      for (int q = 0; q < 32; ++q){
        float hr[8];
        *(f32x4*)&hr[0] = *(const f32x4*)&h[q*8];
        *(f32x4*)&hr[4] = *(const f32x4*)&h[q*8+4];
        a += dot8(*(const uint4v*)(Wh + (size_t)q*6144 + j*8), hr);
      }
    }
    ash[j] = a;
    __syncthreads();
    if (j < 256){
      const float r = sigmoidf_(g0 + a);
      const float z = sigmoidf_(g1 + ash[j+256]);
      const float n = tanhf(g2 + r*ash[j+512]);
      const float hnew = (1.f - z)*n + z*h[j];
      h[j] = hnew;
      encoded[(size_t)(b*TEe + t)*512 + dir*256 + j] = hnew;
    }
    __syncthreads();
  }
}

// encb2[r] = encoded[r,:512] . W2_b
__global__ void k_encb2(const float* __restrict__ encoded, const float* __restrict__ W2b,
                        float* __restrict__ encb2){
  int r = blockIdx.x, l = threadIdx.x;
  const float* e = encoded + (size_t)r*512;
  float s = 0.f;
  for (int k = l; k < 512; k += 64) s += e[k]*W2b[k];
  for (int off = 32; off; off >>= 1) s += __shfl_down(s, off);
  if (l == 0) encb2[r] = s;
}

__global__ void k_hinit(const float* __restrict__ encoded, const int* __restrict__ sizes,
                        const float* __restrict__ W1w, const float* __restrict__ W1b,
                        float* __restrict__ h0){
  int b = blockIdx.x, o = threadIdx.x;
  int idx = sizes[b] - 1;
  idx = idx < 0 ? 0 : (idx > TEe-1 ? TEe-1 : idx);
  const float* ls = encoded + (size_t)(b*TEe + idx)*512;
  const float* wv = W1w + (size_t)o*512;
  float s = W1b[o];
  for (int k = 0; k < 512; k += 4){
    f32x4 a = *(const f32x4*)(ls + k);
    f32x4 w4 = *(const f32x4*)(wv + k);
    s = fmaf(a[0],w4[0], fmaf(a[1],w4[1], fmaf(a[2],w4[2], fmaf(a[3],w4[3], s))));
  }
  h0[b*256 + o] = s;
}

// ---------------- decoder: 32 blocks = batch, 768 threads ----------------
// Whd chunked [32][768][8]; projt chunked [B][16][768][8]; encw2 row-major [B*TE][256] bf16.
// NOTE: ctx-projection gc must stay per-gate OUTSIDE the r* product for the n gate:
//   r = sig(gi_r + gc_r + Wh_r.h + bh_r); n = tanh(gi_n + gc_n + r*(Wh_n.h + bh_n))
#define DJL 112
__global__ __launch_bounds__(768) void k_decoder(
  const unsigned short* __restrict__ Whd, const float* __restrict__ bhd,
  const float* __restrict__ gidx,            // [B][TD][768] f32 (includes bi_d)
  const unsigned short* __restrict__ encw2,  // [B*TE][256] bf16
  const float* __restrict__ encb2,           // [B*TE]
  const unsigned short* __restrict__ projt,  // [B][16][768][8] bf16
  const float* __restrict__ h0,
  unsigned short* __restrict__ outs_bf)      // [B][TD][256] bf16
{
  extern __shared__ char smem[];
  unsigned short* le = (unsigned short*)smem;            // 128*256*2 = 65536
  unsigned short* lw = (unsigned short*)(smem + 65536);  // DJL*512 = 57344
  float* h   = (float*)(smem + 122880);                  // 1024
  float* p   = (float*)(smem + 123904);                  // 512
  float* ash = (float*)(smem + 124416);                  // 3072
  float* gcs = (float*)(smem + 127488);                  // 3072 -> total 130560
  const int b = blockIdx.x, j = threadIdx.x;
  // stage encw2[b] (rows XOR-swizzled)
  for (int cc = j; cc < 128*32; cc += 768){
    int r = cc >> 5, q = cc & 31;
    *(uint4v*)&le[(r*32 + (q ^ (r & 31)))*8] = *(const uint4v*)(encw2 + ((size_t)(b*TEe + r) << 8) + (q << 3));
  }
  // stage Whd rows [0,DJL)
  for (int cc = j; cc < DJL*32; cc += 768){
    int r = cc >> 5, q = cc & 31;
    *(uint4v*)&lw[(r*32 + (q ^ (r & 31)))*8] = *(const uint4v*)(Whd + (size_t)q*6144 + r*8);
  }
  if (j < 256) h[j] = h0[b*256 + j];
  const unsigned short* ptc = projt + (size_t)b*98304;
  const float bhj = bhd[j];
  const int jx = j & 31;
  float gc = 0.f;                             // ctx-projection row j (ctx_init = 0)
  __syncthreads();
  for (int t = 0; t < TDd; ++t){
    float g0 = 0.f, g1 = 0.f, g2 = 0.f;
    if (j < 256){
      const float* grow = gidx + (size_t)(b*TDd + t)*768;
      g0 = grow[j]; g1 = grow[j+256]; g2 = grow[j+512];
    }
    // GRU hidden pre-activation row j: Wh.h + bh  (ctx kept separate in gcs)
    float a = bhj;
    if (j < DJL){
      const unsigned short* lwr = lw + j*256;
      #pragma unroll
      for (int q = 0; q < 32; ++q){
        float hr[8];
        *(f32x4*)&hr[0] = *(const f32x4*)&h[q*8];
        *(f32x4*)&hr[4] = *(const f32x4*)&h[q*8+4];
        a += dot8(*(const uint4v*)(lwr + ((q ^ jx) << 3)), hr);
      }
    } else {
      #pragma unroll
      for (int q = 0; q < 32; ++q){
        float hr[8];
        *(f32x4*)&hr[0] = *(const f32x4*)&h[q*8];
        *(f32x4*)&hr[4] = *(const f32x4*)&h[q*8+4];
        a += dot8(*(const uint4v*)(Whd + (size_t)q*6144 + j*8), hr);
      }
    }
    ash[j] = a;
    gcs[j] = gc;
    __syncthreads();
    if (j < 256){
      const float r = sigmoidf_(g0 + gcs[j] + a);
      const float z = sigmoidf_(g1 + gcs[j+256] + ash[j+256]);
      const float n = tanhf(g2 + gcs[j+512] + r*ash[j+512]);
      const float hnew = (1.f - z)*n + z*h[j];
      h[j] = hnew;
      outs_bf[(size_t)(b*TDd + t)*256 + j] = f2bf(hnew);
    }
    __syncthreads();
    // scores: 128 rows x 4-lane k-split from LDS encw2
    if (j < 512){
      int tt = j >> 2, l = j & 3, tx = tt & 31;
      const unsigned short* er = le + tt*256;
      float s = 0.f;
      #pragma unroll
      for (int i = 0; i < 8; ++i){
        int q = l*8 + i;
        float hr[8];
        *(f32x4*)&hr[0] = *(const f32x4*)&h[q*8];
        *(f32x4*)&hr[4] = *(const f32x4*)&h[q*8+4];
        s += dot8(*(const uint4v*)(er + ((q ^ tx) << 3)), hr);
      }
      s += __shfl_xor(s, 1);
      s += __shfl_xor(s, 2);
      if (l == 0) p[tt] = s + encb2[b*TEe + tt];
    }
    __syncthreads();
    if (j < 64){
      float m = fmaxf(p[j], p[j+64]);
      for (int off = 32; off; off >>= 1) m = fmaxf(m, __shfl_xor(m, off));
      float e0 = __expf(p[j] - m), e1 = __expf(p[j+64] - m);
      float ssum = e0 + e1;
      for (int off = 32; off; off >>= 1) ssum += __shfl_xor(ssum, off);
      float inv = 1.f / ssum;
      p[j] = e0*inv; p[j+64] = e1*inv;
    }
    __syncthreads();
    // ctx-projection for NEXT step: gc = dot(projt[b] row j over 128 enc pos, p)
    gc = 0.f;
    #pragma unroll
    for (int q = 0; q < 16; ++q){
      float pr[8];
      *(f32x4*)&pr[0] = *(const f32x4*)&p[q*8];
      *(f32x4*)&pr[4] = *(const f32x4*)&p[q*8+4];
      gc += dot8(*(const uint4v*)(ptc + (size_t)q*6144 + j*8), pr);
    }
    // no sync needed: p is re-written only after next step's two syncs
  }
}

extern "C" void kernel_launch(void* const* d_in, const int* in_sizes, int n_in,
                              void* d_out, int out_size, void* d_ws, size_t ws_size,
                              hipStream_t stream)
{
  (void)in_sizes; (void)n_in; (void)out_size;
  const int*   enc_in = (const int*)d_in[0];
  const int*   dec_in = (const int*)d_in[1];
  const float* embW   = (const float*)d_in[2];
  const float* Wi_f   = (const float*)d_in[3];
  const float* Wh_f   = (const float*)d_in[4];
  const float* bi_f   = (const float*)d_in[5];
  const float* bh_f   = (const float*)d_in[6];
  const float* Wi_b   = (const float*)d_in[7];
  const float* Wh_b   = (const float*)d_in[8];
  const float* bi_b   = (const float*)d_in[9];
  const float* bh_b   = (const float*)d_in[10];
  const float* Wi_d   = (const float*)d_in[11];
  const float* Wh_d   = (const float*)d_in[12];
  const float* bi_d   = (const float*)d_in[13];
  const float* bh_d   = (const float*)d_in[14];
  const float* W1_w   = (const float*)d_in[15];
  const float* W1_b   = (const float*)d_in[16];
  const float* W2_w   = (const float*)d_in[17];
  const float* W2_b   = (const float*)d_in[18];
  const float* lin_w  = (const float*)d_in[19];
  const float* lin_b  = (const float*)d_in[20];

  char* scr = (char*)d_out;
  float* emb_enc = (float*)(scr + 0);
  float* emb_dec = (float*)(scr + 4194304);
  float* gi_f    = (float*)(scr + 6291456);
  float* gi_b    = (float*)(scr + 18874368);
  float* gi_dx   = (float*)(scr + 31457280);
  float* enc     = (float*)(scr + 37748736);
  float* projf   = (float*)(scr + 46137344);
  unsigned short* whf_bf = (unsigned short*)(scr + 58720256);
  unsigned short* whb_bf = (unsigned short*)(scr + 59113472);
  unsigned short* whd_bf = (unsigned short*)(scr + 59506688);
  unsigned short* encw2  = (unsigned short*)(scr + 59899904);
  unsigned short* projt  = (unsigned short*)(scr + 61997056);
  float* encb2 = (float*)(scr + 68288512);
  int*   sizes = (int*)(scr + 68304896);
  float* h0    = (float*)(scr + 68305024);

  unsigned short* outs_bf = (unsigned short*)d_ws;
  unsigned short* lin_bf  = (unsigned short*)((char*)d_ws + (1<<20));
  const bool big = ws_size >= (size_t)(1<<20) + 16384000u + 1024u;

  // allow >64KB dynamic LDS (capture-safe host-side attribute; idempotent)
  hipFuncSetAttribute((const void*)k_encoder, hipFuncAttributeMaxDynamicSharedMemorySize, 131072);
  hipFuncSetAttribute((const void*)k_decoder, hipFuncAttributeMaxDynamicSharedMemorySize, 130560);

  k_sizes<<<1, 32, 0, stream>>>(enc_in, sizes);
  k_gather<<<Bb*TEe, 256, 0, stream>>>(enc_in, embW, emb_enc, Bb*TEe);
  k_gather<<<Bb*TDd, 256, 0, stream>>>(dec_in, embW, emb_dec, Bb*TDd);
  k_chunkw<<<768, 256, 0, stream>>>(Wh_f, whf_bf, 768);
  k_chunkw<<<768, 256, 0, stream>>>(Wh_b, whb_bf, 768);
  k_chunkw<<<768, 256, 0, stream>>>(Wh_d, whd_bf, 768);
  if (big) k_extract_bf16<<<32000, 256, 0, stream>>>(lin_w, lin_bf, 32000*256);

  k_gemm<false,false,false,false><<<dim3(6,32), 256, 0, stream>>>(
      emb_enc, Wi_f, bi_f, gi_f, 4096, 768, 256, 256, 256, 768);
  k_gemm<false,false,false,false><<<dim3(6,32), 256, 0, stream>>>(
      emb_enc, Wi_b, bi_b, gi_b, 4096, 768, 256, 256, 256, 768);
  k_gemm<false,false,false,false><<<dim3(6,16), 256, 0, stream>>>(
      emb_dec, Wi_d + 512, bi_d, gi_dx, 2048, 768, 256, 256, 768, 768);

  k_encoder<<<64, 768, 131072, stream>>>(whf_bf, whb_bf, bh_f, bh_b, gi_f, gi_b, enc);
  k_encb2<<<Bb*TEe, 64, 0, stream>>>(enc, W2_b, encb2);

  k_gemm<false,false,true,true><<<dim3(2,32), 256, 0, stream>>>(
      enc, W2_w, nullptr, encw2, 4096, 256, 512, 512, 256, 256);
  k_gemm<false,false,false,false><<<dim3(6,32), 256, 0, stream>>>(
      enc, Wi_d, nullptr, projf, 4096, 768, 512, 512, 768, 768);
  k_projchunk<<<(Bb*16*768*8)/256, 256, 0, stream>>>(projf, projt);
  k_hinit<<<Bb, 256, 0, stream>>>(enc, sizes, W1_w, W1_b, h0);

  k_decoder<<<Bb, 768, 130560, stream>>>(whd_bf, bh_d, gi_dx, encw2, encb2, projt, h0, outs_bf);

  if (big)
    k_gemm<true,true,false,false><<<dim3(250,16), 256, 0, stream>>>(
        outs_bf, lin_bf, lin_b, d_out, 2048, 32000, 256, 256, 256, 32000);
  else
    k_gemm<true,false,false,false><<<dim3(250,16), 256, 0, stream>>>(
        outs_bf, lin_w, lin_b, d_out, 2048, 32000, 256, 256, 256, 32000);
}